// Round 8
// baseline (1803.628 us; speedup 1.0000x reference)
//
#include <hip/hip_runtime.h>
#include <stdint.h>

// AutomatonNetwork: 4096-step vecmat chain lifted to a bf16 MFMA product tree.
// Round-8: kk-ring PHASE ROTATION. Round-7 analysis: step time 49k cyc vs
// MFMA 19.9k / LDS 12.3k floors -> bound by effective L2 BW (~11 TB/s of
// 34.5): the 8 strips of a chain stream the SAME token matrix in lockstep,
// hot-spotting one L2 channel at a time. Fix: each strip starts the (order-
// independent) 16-slice K accumulation ring at its own phase (kk=(i+2*strip)
// &15), spreading concurrent reads across channels. Total bytes unchanged.
// Everything else identical to round 7 (proven: absmax 1.5e-5).

typedef unsigned short ushort_t;
typedef __attribute__((ext_vector_type(8))) short v8s;    // 8 bf16 MFMA frag
typedef __attribute__((ext_vector_type(4))) float f32x4;  // MFMA 16x16 acc

#define NSTATE 512
#define NSYM   128
#define LTOK   4096
#define MS     ((size_t)NSTATE*NSTATE)

__device__ __forceinline__ ushort_t f2bf(float f){
  unsigned u = __float_as_uint(f);
  u = u + 0x7FFFu + ((u >> 16) & 1u);    // RNE
  return (ushort_t)(u >> 16);
}
__device__ __forceinline__ float bf2f(ushort_t h){
  return __uint_as_float(((unsigned)h) << 16);
}
// fragment-major: element (m, k) of M^T (i.e. M[k][m]) at:
__device__ __forceinline__ size_t fragT_idx(int m, int k){
  return ((size_t)((k >> 5)*512 + m)*4 + ((k >> 3) & 3))*8 + (k & 7);
}

// ---------------------------------------------------------------------------
// 64-row engine with phased K-ring. Strip = 64x512 running product in LDS
// (swizzled: chunk p holds true chunk p^(n&7)). D = Btok^T * Strip^T.
//   A-frag: global fragT, contiguous 1 KiB per wave load (coalesced)
//   B-frag: strip row n = nt*16+l15, chunk kk*4+q4 (xor n&7)
//   D: acc[mt][nt][i] = newstrip[n][wv*64+mt*16+q4*4+i]
// kk visits (i+phase)&15 — accumulation order-independent. Layouts HW-proven.
// ---------------------------------------------------------------------------
__device__ __forceinline__ void step_mfma64(f32x4 acc[4][4],
    const ushort_t* __restrict__ As, const ushort_t* __restrict__ Bf,
    int wv, int l15, int q4, int phase){
  const ushort_t* base = Bf + ((size_t)(wv*64 + l15)*4 + q4)*8;
  v8s aA[4], aN[4];
  {
    const int kk0 = phase & 15;
    #pragma unroll
    for (int mt = 0; mt < 4; ++mt)
      aA[mt] = *(const v8s*)&base[(size_t)kk0*16384 + mt*512];
  }
  #pragma unroll
  for (int i = 0; i < 16; ++i){
    const int kk = (i + phase) & 15;
    if (i < 15){
      const int kn = (i + 1 + phase) & 15;
      #pragma unroll
      for (int mt = 0; mt < 4; ++mt)
        aN[mt] = *(const v8s*)&base[(size_t)kn*16384 + mt*512];
    }
    #pragma unroll
    for (int nt = 0; nt < 4; ++nt){
      int n  = nt*16 + l15;
      int ch = kk*4 + q4;
      v8s bf = *(const v8s*)&As[n*512 + ((ch ^ (n & 7))*8)];
      #pragma unroll
      for (int mt = 0; mt < 4; ++mt)
        acc[mt][nt] = __builtin_amdgcn_mfma_f32_16x16x32_bf16(aA[mt], bf, acc[mt][nt], 0,0,0);
    }
    #pragma unroll
    for (int mt = 0; mt < 4; ++mt) aA[mt] = aN[mt];
  }
}

__device__ __forceinline__ void load_strip64(ushort_t* As,
    const ushort_t* __restrict__ src, int rowbase, int tid){
  #pragma unroll
  for (int q = 0; q < 8; ++q){
    int F = tid + q*512;
    int m = F >> 6, p = F & 63;
    *(v8s*)&As[m*512 + p*8] =
      *(const v8s*)&src[(size_t)(rowbase + m)*NSTATE + ((p ^ (m & 7))*8)];
  }
}

__device__ __forceinline__ void writeback64(ushort_t* As, f32x4 acc[4][4],
    int wv, int l15, int q4){
  #pragma unroll
  for (int nt = 0; nt < 4; ++nt){
    int n = nt*16 + l15;
    #pragma unroll
    for (int mt = 0; mt < 4; ++mt){
      int col = wv*64 + mt*16 + q4*4;
      ushort4 h;
      h.x = f2bf(acc[mt][nt][0]); h.y = f2bf(acc[mt][nt][1]);
      h.z = f2bf(acc[mt][nt][2]); h.w = f2bf(acc[mt][nt][3]);
      int p = (col >> 3) ^ (n & 7);
      *(ushort4*)&As[n*512 + p*8 + (col & 7)] = h;
    }
  }
}

// final store: even -> row-major; odd -> fragment-major transposed
__device__ __forceinline__ void store_out64(ushort_t* slot, f32x4 acc[4][4],
    int rowbase, bool even, int lane, int wv, int l15, int q4){
  if (even){
    #pragma unroll
    for (int nt = 0; nt < 4; ++nt){
      int grow = rowbase + nt*16 + l15;
      #pragma unroll
      for (int mt = 0; mt < 4; ++mt){
        int gcol = wv*64 + mt*16 + q4*4;
        ushort4 h;
        h.x = f2bf(acc[mt][nt][0]); h.y = f2bf(acc[mt][nt][1]);
        h.z = f2bf(acc[mt][nt][2]); h.w = f2bf(acc[mt][nt][3]);
        *(ushort4*)&slot[(size_t)grow*NSTATE + gcol] = h;
      }
    }
  } else {
    // 4x4 quad butterfly (HW-proven rounds 5-7): lane ends with
    // d[i] = C[G0+i][mcol], contiguous in fragT (k = G0..G0+3)
    #pragma unroll
    for (int nt = 0; nt < 4; ++nt){
      int G0 = rowbase + nt*16 + (l15 & 12);
      #pragma unroll
      for (int mt = 0; mt < 4; ++mt){
        float v0 = acc[mt][nt][0], v1 = acc[mt][nt][1];
        float v2 = acc[mt][nt][2], v3 = acc[mt][nt][3];
        float s0 = __shfl_xor(v0, 2), s1 = __shfl_xor(v1, 2);
        float s2 = __shfl_xor(v2, 2), s3 = __shfl_xor(v3, 2);
        const bool h2 = lane & 2;
        float c0 = h2 ? s2 : v0, c1 = h2 ? s3 : v1;
        float c2 = h2 ? v2 : s0, c3 = h2 ? v3 : s1;
        float u0 = __shfl_xor(c0, 1), u1 = __shfl_xor(c1, 1);
        float u2 = __shfl_xor(c2, 1), u3 = __shfl_xor(c3, 1);
        const bool h1 = lane & 1;
        float d0 = h1 ? u1 : c0, d1 = h1 ? c1 : u0;
        float d2 = h1 ? u3 : c2, d3 = h1 ? c3 : u2;
        int mcol = wv*64 + mt*16 + q4*4 + (lane & 3);
        ushort4 h;
        h.x = f2bf(d0); h.y = f2bf(d1); h.z = f2bf(d2); h.w = f2bf(d3);
        *(ushort4*)&slot[fragT_idx(mcol, G0)] = h;
      }
    }
  }
}

// Chains: WG (c, strip) holds 64 rows of chain c's product in LDS across all
// W-1 steps. 8 strips of a chain share one XCD (b&7 = XCD affinity); each
// strip walks the K-ring at its own phase (2*strip) to spread L2 channels.
__global__ __launch_bounds__(512, 4) void k_chain3(
    const int* __restrict__ tokens, const ushort_t* __restrict__ Tb,
    const ushort_t* __restrict__ Tf, ushort_t* __restrict__ Lout, int W){
  extern __shared__ __align__(16) ushort_t As[];   // 64x512 bf16
  const int b = blockIdx.x;
  const int c       = (b >> 6) * 8 + (b & 7);
  const int strip   = (b >> 3) & 7;
  const int rowbase = strip * 64;
  const int phase   = strip * 2;
  const int tid  = threadIdx.x;
  const int lane = tid & 63;
  const int wv   = tid >> 6;
  const int l15  = lane & 15;
  const int q4   = lane >> 4;
  const int t0   = c * W;

  load_strip64(As, Tb + (size_t)tokens[t0] * MS, rowbase, tid);
  __syncthreads();
  for (int k = 1; k < W; ++k){
    f32x4 acc[4][4];
    #pragma unroll
    for (int mt = 0; mt < 4; ++mt)
      #pragma unroll
      for (int nt = 0; nt < 4; ++nt) acc[mt][nt] = (f32x4){0.f,0.f,0.f,0.f};
    step_mfma64(acc, As, Tf + (size_t)tokens[t0 + k] * MS, wv, l15, q4, phase);
    __syncthreads();                   // strip reads done
    if (k < W - 1){
      writeback64(As, acc, wv, l15, q4);
      __syncthreads();                 // new strip visible
    } else {
      store_out64(Lout + (size_t)c * MS, acc, rowbase, !(c & 1), lane, wv, l15, q4);
    }
  }
}

// One tree level: Ldst[j] = Lsrc[2j](RM) @ Lsrc[2j+1](fragT), 8 strips/node,
// phased K-ring per strip.
__global__ __launch_bounds__(512, 4) void k_tree3(
    const ushort_t* __restrict__ Lsrc, ushort_t* __restrict__ Ldst){
  extern __shared__ __align__(16) ushort_t As[];
  const int b = blockIdx.x;
  int j, strip;
  if (gridDim.x >= 64){ j = (b >> 6) * 8 + (b & 7); strip = (b >> 3) & 7; }
  else                { j = b >> 3;                  strip = b & 7; }
  const int rowbase = strip * 64;
  const int phase   = strip * 2;
  const int tid  = threadIdx.x;
  const int lane = tid & 63;
  const int wv   = tid >> 6;
  const int l15  = lane & 15;
  const int q4   = lane >> 4;
  load_strip64(As, Lsrc + (size_t)(2*j) * MS, rowbase, tid);
  __syncthreads();
  f32x4 acc[4][4];
  #pragma unroll
  for (int mt = 0; mt < 4; ++mt)
    #pragma unroll
    for (int nt = 0; nt < 4; ++nt) acc[mt][nt] = (f32x4){0.f,0.f,0.f,0.f};
  step_mfma64(acc, As, Lsrc + (size_t)(2*j + 1) * MS, wv, l15, q4, phase);
  store_out64(Ldst + (size_t)j * MS, acc, rowbase, !(j & 1), lane, wv, l15, q4);
}

// transfer f32 -> Tb (bf16 row-major) + Tf (bf16 fragment-major transposed)
__global__ __launch_bounds__(256) void k_prep(const float* __restrict__ transfer,
                                              ushort_t* __restrict__ Tb,
                                              ushort_t* __restrict__ Tf){
  __shared__ ushort_t t[32*512];
  const int s = blockIdx.x >> 4;
  const int kk = blockIdx.x & 15;                  // K-band [32kk,+32)
  const int krows = kk * 32;
  const int tid = threadIdx.x;
  for (int idx = tid; idx < 32*512; idx += 256){
    int r = idx >> 9, n = idx & 511;
    ushort_t h = f2bf(transfer[(size_t)s*MS + (size_t)(krows + r)*NSTATE + n]);
    Tb[(size_t)s*MS + (size_t)(krows + r)*NSTATE + n] = h;
    t[r*512 + n] = h;
  }
  __syncthreads();
  for (int idx = tid; idx < 512*4; idx += 256){
    int n = idx >> 2, cc = idx & 3;
    v8s vv;
    #pragma unroll
    for (int jj = 0; jj < 8; ++jj) vv[jj] = (short)t[(cc*8 + jj)*512 + n];
    *(v8s*)&Tf[(size_t)s*MS + ((size_t)(kk*512 + n)*4 + cc)*8] = vv;
  }
}

// ---------------------------------------------------------------------------
// Fallback path (no big-LDS): proven gemm_step with fragT B.
// ---------------------------------------------------------------------------
__device__ __forceinline__ void gl_lds16(const void* g, void* l){
  __builtin_amdgcn_global_load_lds(
      (const __attribute__((address_space(1))) unsigned int*)g,
      (__attribute__((address_space(3))) unsigned int*)l, 16, 0, 0);
}

__device__ void gemm_step(const ushort_t* __restrict__ A,
                          const ushort_t* __restrict__ Bf,
                          ushort_t* dRM, ushort_t* dT, int rowbase){
  __shared__ __align__(16) ushort_t ldsA[128*64];
  __shared__ __align__(16) ushort_t ldsB[128*64];
  const int tid  = threadIdx.x;
  const int lane = tid & 63;
  const int w    = tid >> 6;
  const int l15  = lane & 15;
  const int koff = (lane >> 4) * 8;

  __threadfence_block();

  for (int p = 0; p < 4; ++p){
    f32x4 acc[2][8];
    #pragma unroll
    for (int rt = 0; rt < 2; ++rt)
      #pragma unroll
      for (int ct = 0; ct < 8; ++ct) acc[rt][ct] = (f32x4){0.f,0.f,0.f,0.f};

    for (int kk = 0; kk < 8; ++kk){
      __syncthreads();
      #pragma unroll
      for (int q = 0; q < 4; ++q){
        int idx = tid + q*256;
        int rr = idx >> 3, cch = idx & 7;
        gl_lds16(&A [(size_t)(rowbase + rr)*NSTATE + kk*64 + cch*8], &ldsA[idx*8]);
        gl_lds16(&Bf[fragT_idx(p*128 + rr, kk*64 + cch*8)], &ldsB[idx*8]);
      }
      __syncthreads();
      #pragma unroll
      for (int kc = 0; kc < 2; ++kc){
        v8s a0 = *(const v8s*)&ldsA[(w*32 +      l15)*64 + kc*32 + koff];
        v8s a1 = *(const v8s*)&ldsA[(w*32 + 16 + l15)*64 + kc*32 + koff];
        #pragma unroll
        for (int ct = 0; ct < 8; ++ct){
          v8s bb = *(const v8s*)&ldsB[(ct*16 + l15)*64 + kc*32 + koff];
          acc[0][ct] = __builtin_amdgcn_mfma_f32_16x16x32_bf16(a0, bb, acc[0][ct], 0,0,0);
          acc[1][ct] = __builtin_amdgcn_mfma_f32_16x16x32_bf16(a1, bb, acc[1][ct], 0,0,0);
        }
      }
    }
    const int rb = rowbase + w*32 + (lane >> 4)*4;
    #pragma unroll
    for (int rt = 0; rt < 2; ++rt)
      #pragma unroll
      for (int ct = 0; ct < 8; ++ct)
        #pragma unroll
        for (int i = 0; i < 4; ++i){
          int grow = rb + rt*16 + i;
          int gcol = p*128 + ct*16 + l15;
          ushort_t h = f2bf(acc[rt][ct][i]);
          if (dRM) dRM[(size_t)grow*NSTATE + gcol] = h;
          if (dT)  dT [fragT_idx(gcol, grow)] = h;
        }
  }
  __syncthreads();
}

__global__ __launch_bounds__(256) void k_chain(const int* __restrict__ tokens,
    const ushort_t* __restrict__ Tb, const ushort_t* __restrict__ Tf,
    ushort_t* ping, ushort_t* pong, ushort_t* Lout, int W){
  const int c = blockIdx.x >> 2;
  const int r = blockIdx.x & 3;
  const int t0 = c * W;
  ushort_t* bufA = ping + (size_t)c * MS;
  ushort_t* bufB = pong + (size_t)c * MS;
  for (int k = 1; k < W; ++k){
    const ushort_t* Asrc = (k == 1) ? Tb + (size_t)tokens[t0] * MS
                                    : (((k - 1) & 1) ? bufA : bufB);
    ushort_t *dRM, *dT;
    if (k == W - 1){
      ushort_t* slot = Lout + (size_t)c * MS;
      dRM = (c & 1) ? nullptr : slot;
      dT  = (c & 1) ? slot    : nullptr;
    } else {
      dRM = (k & 1) ? bufA : bufB; dT = nullptr;
    }
    gemm_step(Asrc, Tf + (size_t)tokens[t0 + k] * MS, dRM, dT, r * 128);
  }
}

__global__ __launch_bounds__(256) void k_tree(const ushort_t* __restrict__ Lsrc,
                                              ushort_t* __restrict__ Ldst){
  const int j = blockIdx.x >> 2, r = blockIdx.x & 3;
  const ushort_t* A  = Lsrc + (size_t)(2*j)     * MS;
  const ushort_t* Bf = Lsrc + (size_t)(2*j + 1) * MS;
  ushort_t* slot = Ldst + (size_t)j * MS;
  gemm_step(A, Bf, (j & 1) ? nullptr : slot, (j & 1) ? slot : nullptr, r * 128);
}

// Boundary vectors u_g via binary decomposition over tree levels baseLvl..11.
// Node index (pos>>p) always even -> row-major form available.
__global__ __launch_bounds__(512) void k_descent(const float* __restrict__ start,
    const ushort_t* __restrict__ lvl4, const ushort_t* __restrict__ Upper,
    float* __restrict__ u, int baseLvl){
  __shared__ float v[NSTATE];
  const int upOff[7] = {0,128,192,224,240,248,252};
  const int g = blockIdx.x, tid = threadIdx.x;
  v[tid] = start[tid];
  __syncthreads();
  int pos = 0;
  for (int p = 11 - baseLvl; p >= 0; --p){
    if ((g >> p) & 1){
      const int L = baseLvl + p;
      const ushort_t* arr = (L == 4) ? lvl4 : (Upper + (size_t)upOff[L-5] * MS);
      const ushort_t* M = arr + (size_t)(pos >> p) * MS;
      float a0=0.f,a1=0.f,a2=0.f,a3=0.f;
      #pragma unroll 4
      for (int i = 0; i < NSTATE; i += 4){
        a0 += v[i  ] * bf2f(M[(size_t)(i  )*NSTATE + tid]);
        a1 += v[i+1] * bf2f(M[(size_t)(i+1)*NSTATE + tid]);
        a2 += v[i+2] * bf2f(M[(size_t)(i+2)*NSTATE + tid]);
        a3 += v[i+3] * bf2f(M[(size_t)(i+3)*NSTATE + tid]);
      }
      __syncthreads();
      v[tid] = (a0+a1)+(a2+a3);
      __syncthreads();
      pos += 1 << p;
    }
  }
  u[(size_t)g*NSTATE + tid] = v[tid];
}

// Per-segment replay with fragT vector loads: thread tid = output column m;
// M[k][m] for 32 consecutive k is 64 contiguous bytes in Tf.
__global__ __launch_bounds__(512) void k_phase2(const int* __restrict__ tokens,
    const float* __restrict__ u, const ushort_t* __restrict__ Tf,
    const float* __restrict__ probs, float* __restrict__ partials,
    float* __restrict__ out, int SEG){
  __shared__ float v[NSTATE];
  __shared__ float redc[8], redm[8];
  __shared__ float fac, minv;
  const int g = blockIdx.x, tid = threadIdx.x;
  v[tid] = u[(size_t)g*NSTATE + tid];
  float pp = 1.f;
  __syncthreads();
  for (int k = 0; k < SEG; ++k){
    const int tok = tokens[g*SEG + k];
    float a = v[tid];
    float bb = a * probs[(size_t)tok*NSTATE + tid];
    #pragma unroll
    for (int o = 32; o > 0; o >>= 1){
      a  += __shfl_down(a, o);
      bb += __shfl_down(bb, o);
    }
    if ((tid & 63) == 0){ redm[tid >> 6] = a; redc[tid >> 6] = bb; }
    __syncthreads();
    if (tid == 0){
      float m = 0.f, cc = 0.f;
      #pragma unroll
      for (int q = 0; q < 8; ++q){ m += redm[q]; cc += redc[q]; }
      fac = cc / m;
    }
    __syncthreads();
    pp *= fac;
    const ushort_t* Mf = Tf + (size_t)tok * MS + (size_t)tid * 32;
    float a0=0.f,a1=0.f,a2=0.f,a3=0.f;
    for (int bnd = 0; bnd < 16; ++bnd){
      const v8s* pv = (const v8s*)&Mf[(size_t)bnd*16384];
      v8s h0 = pv[0], h1 = pv[1], h2 = pv[2], h3 = pv[3];
      const float* vb = &v[bnd*32];
      #pragma unroll
      for (int j = 0; j < 8; ++j){
        a0 += vb[j     ] * bf2f((ushort_t)h0[j]);
        a1 += vb[j +  8] * bf2f((ushort_t)h1[j]);
        a2 += vb[j + 16] * bf2f((ushort_t)h2[j]);
        a3 += vb[j + 24] * bf2f((ushort_t)h3[j]);
      }
    }
    __syncthreads();
    v[tid] = (a0+a1)+(a2+a3);
    __syncthreads();
  }
  if (tid == 0) partials[g] = pp;
  if (g == gridDim.x - 1){
    float a = v[tid];
    #pragma unroll
    for (int o = 32; o > 0; o >>= 1) a += __shfl_down(a, o);
    if ((tid & 63) == 0) redm[tid >> 6] = a;
    __syncthreads();
    if (tid == 0){
      float m = 0.f;
      #pragma unroll
      for (int q = 0; q < 8; ++q) m += redm[q];
      minv = 1.f / m;
    }
    __syncthreads();
    out[tid] = v[tid] * minv;
  }
}

__global__ __launch_bounds__(512) void k_finish(const float* __restrict__ partials,
    const float* __restrict__ finals, float* out, int G){
  __shared__ float red[8];
  const int tid = threadIdx.x;
  float x = out[tid] * finals[tid];
  #pragma unroll
  for (int o = 32; o > 0; o >>= 1) x += __shfl_down(x, o);
  if ((tid & 63) == 0) red[tid >> 6] = x;
  __syncthreads();
  if (tid == 0){
    float s = 0.f;
    for (int q = 0; q < 8; ++q) s += red[q];
    float pp = 1.f;
    for (int q = 0; q < G; ++q) pp *= partials[q];
    out[NSTATE] = pp * s;
  }
}

__global__ __launch_bounds__(512) void k_fallback(const int* __restrict__ tokens,
    const float* __restrict__ start, const float* __restrict__ transfer,
    const float* __restrict__ probs, const float* __restrict__ finals,
    float* out){
  __shared__ float v[NSTATE];
  __shared__ float red[9];
  const int tid = threadIdx.x;
  v[tid] = start[tid];
  float pp = 1.f;
  __syncthreads();
  for (int t = 0; t < LTOK; ++t){
    const int tok = tokens[t];
    float x = v[tid] * probs[(size_t)tok*NSTATE + tid];
    #pragma unroll
    for (int o = 32; o > 0; o >>= 1) x += __shfl_down(x, o);
    if ((tid & 63) == 0) red[tid >> 6] = x;
    __syncthreads();
    if (tid == 0){
      float cc = 0.f;
      for (int q = 0; q < 8; ++q) cc += red[q];
      red[8] = cc;
    }
    __syncthreads();
    pp *= red[8];
    const float* M = transfer + (size_t)tok * MS;
    float acc = 0.f;
    #pragma unroll 8
    for (int i = 0; i < NSTATE; ++i) acc += v[i] * M[(size_t)i*NSTATE + tid];
    __syncthreads();
    v[tid] = acc;
    __syncthreads();
  }
  out[tid] = v[tid];
  float x = v[tid] * finals[tid];
  #pragma unroll
  for (int o = 32; o > 0; o >>= 1) x += __shfl_down(x, o);
  if ((tid & 63) == 0) red[tid >> 6] = x;
  __syncthreads();
  if (tid == 0){
    float s = 0.f;
    for (int q = 0; q < 8; ++q) s += red[q];
    out[NSTATE] = pp * s;
  }
}

extern "C" void kernel_launch(void* const* d_in, const int* in_sizes, int n_in,
                              void* d_out, int out_size, void* d_ws, size_t ws_size,
                              hipStream_t stream) {
  const int*   tokens   = (const int*)  d_in[0];
  const float* start    = (const float*)d_in[1];
  const float* transfer = (const float*)d_in[2];
  const float* probs    = (const float*)d_in[3];
  const float* finals   = (const float*)d_in[4];
  float* out = (float*)d_out;
  (void)in_sizes; (void)n_in; (void)out_size;

  const size_t C2 = MS * 2;
  size_t off = 0;
  const size_t o_Tb    = off; off += C2 * NSYM;    // 64 MiB
  const size_t o_Tf    = off; off += C2 * NSYM;    // 64 MiB
  const size_t o_Upper = off; off += C2 * 254;     // 127 MiB (tree levels 5..11)
  const size_t o_u     = off; off += (size_t)256 * NSTATE * 4;
  const size_t o_part  = off; off += 256 * 4 + 256;
  const size_t common  = off;                      // ~255.4 MiB

  const int LDSBYTES = 64*512*2;                   // 65536
  bool bigLds =
    hipFuncSetAttribute(reinterpret_cast<const void*>(k_chain3),
        hipFuncAttributeMaxDynamicSharedMemorySize, LDSBYTES) == hipSuccess &&
    hipFuncSetAttribute(reinterpret_cast<const void*>(k_tree3),
        hipFuncAttributeMaxDynamicSharedMemorySize, LDSBYTES) == hipSuccess;

  char* ws = (char*)d_ws;
  ushort_t* Tb    = (ushort_t*)(ws + o_Tb);
  ushort_t* Tf    = (ushort_t*)(ws + o_Tf);
  ushort_t* Upper = (ushort_t*)(ws + o_Upper);
  float*    u     = (float*)   (ws + o_u);
  float*    parts = (float*)   (ws + o_part);

  const int upOff[7] = {0,128,192,224,240,248,252};
  ushort_t* lvl[12] = {nullptr};
  for (int l = 5; l <= 11; ++l) lvl[l] = Upper + (size_t)upOff[l-5] * MS;

  int W = 0, sLvl = 0;
  size_t oo = common;
  if (bigLds){
    if      (ws_size >= common + C2 * (512 + 256)) { W = 8;  sLvl = 3; }
    else if (ws_size >= common + C2 * 256)         { W = 16; sLvl = 4; }
    else if (ws_size >= common)                    { W = 32; sLvl = 5; }
    if (W){
      if (W == 8) { lvl[3] = (ushort_t*)(ws + oo); oo += C2 * 512; }
      if (W <= 16){ lvl[4] = (ushort_t*)(ws + oo); oo += C2 * 256; }
    }
  } else {
    if (ws_size >= common + C2 * 256) { W = 32; sLvl = 5; }
  }
  if (!W){
    k_fallback<<<1, 512, 0, stream>>>(tokens, start, transfer, probs, finals, out);
    return;
  }
  const int nchain = LTOK / W;
  const int G    = lvl[4] ? 256 : 128;
  const int SEGc = LTOK / G;
  const int baseLvl = lvl[4] ? 4 : 5;

  k_prep<<<NSYM * 16, 256, 0, stream>>>(transfer, Tb, Tf);
  if (bigLds){
    k_chain3<<<nchain * 8, 512, LDSBYTES, stream>>>(tokens, Tb, Tf, lvl[sLvl], W);
    for (int l = sLvl; l < 11; ++l){
      const int cntNext = LTOK >> (l + 1);
      k_tree3<<<cntNext * 8, 512, LDSBYTES, stream>>>(lvl[l], lvl[l + 1]);
    }
  } else {
    ushort_t* ping = (ushort_t*)(ws + oo); oo += C2 * nchain;
    ushort_t* pong = (ushort_t*)(ws + oo); oo += C2 * nchain;
    k_chain<<<nchain * 4, 256, 0, stream>>>(tokens, Tb, Tf, ping, pong, lvl[sLvl], W);
    for (int l = sLvl; l < 11; ++l){
      const int cntNext = LTOK >> (l + 1);
      k_tree<<<cntNext * 4, 256, 0, stream>>>(lvl[l], lvl[l + 1]);
    }
  }
  k_descent<<<G, 512, 0, stream>>>(start, lvl[4], Upper, u, baseLvl);
  k_phase2 <<<G, 512, 0, stream>>>(tokens, u, Tf, probs, parts, out, SEGc);
  k_finish <<<1, 512, 0, stream>>>(parts, finals, out, G);
}

// Round 9
// 1799.998 us; speedup vs baseline: 1.0020x; 1.0020x over previous
//
#include <hip/hip_runtime.h>
#include <stdint.h>

// AutomatonNetwork: 4096-step vecmat chain lifted to a bf16 MFMA product tree.
// Round-9: same-chain CU pairing. Rounds 6/7/8 showed two walls at ~1150 us:
// 1 WG/CU = barrier-bound, 2 WG/CU = L2-service-bound (16 GB A-stream, only
// 8x XCD-level reuse). Fix: hierarchical block mapping puts (a) all 8 strips
// of a chain on one XCD (4 MiB L2 set, 8x L2 reuse) AND (b) strip pairs
// (2t,2t+1) co-resident on ONE CU -> identical, time-aligned A-streams; the
// second WG hits L1 (per-kk slice = 32 KiB = L1 size). Lockstep phases
// restored (round-8 rotation raised FETCH). Plus cross-step A-prefetch: the
// last K-slot prefetches next token's slice 0 across the writeback barriers.
// Numerics: emission factors (v.p)/(sum v) cancel bf16 mass drift (proven,
// absmax 1.5e-5 vs 4e-3 threshold, rounds 2-8).

typedef unsigned short ushort_t;
typedef __attribute__((ext_vector_type(8))) short v8s;    // 8 bf16 MFMA frag
typedef __attribute__((ext_vector_type(4))) float f32x4;  // MFMA 16x16 acc

#define NSTATE 512
#define NSYM   128
#define LTOK   4096
#define MS     ((size_t)NSTATE*NSTATE)

__device__ __forceinline__ ushort_t f2bf(float f){
  unsigned u = __float_as_uint(f);
  u = u + 0x7FFFu + ((u >> 16) & 1u);    // RNE
  return (ushort_t)(u >> 16);
}
__device__ __forceinline__ float bf2f(ushort_t h){
  return __uint_as_float(((unsigned)h) << 16);
}
// fragment-major: element (m, k) of M^T (i.e. M[k][m]) at:
__device__ __forceinline__ size_t fragT_idx(int m, int k){
  return ((size_t)((k >> 5)*512 + m)*4 + ((k >> 3) & 3))*8 + (k & 7);
}

// ---------------------------------------------------------------------------
// 64-row engine. Strip = 64x512 running product in LDS (swizzled: chunk p
// holds true chunk p^(n&7)). D = Btok^T * Strip^T.
//   A-frag: global fragT, contiguous 1 KiB per wave load (coalesced)
//   B-frag: strip row n = nt*16+l15, chunk kk*4+q4 (xor n&7)
//   D: acc[mt][nt][i] = newstrip[n][wv*64+mt*16+q4*4+i]
// Layouts HW-proven rounds 2-8.
// ---------------------------------------------------------------------------

// chain variant: aA persists across steps; slot i=15 prefetches baseN slice 0
// (in flight across the writeback barriers).
__device__ __forceinline__ void step_mfma64_pf(f32x4 acc[4][4],
    const ushort_t* __restrict__ As, const ushort_t* __restrict__ basek,
    const ushort_t* __restrict__ baseN, v8s aA[4],
    int wv, int l15, int q4){
  #pragma unroll
  for (int i = 0; i < 16; ++i){
    v8s aN[4];
    const ushort_t* src = (i < 15) ? (basek + (size_t)(i + 1)*16384) : baseN;
    #pragma unroll
    for (int mt = 0; mt < 4; ++mt)
      aN[mt] = *(const v8s*)&src[mt*512];
    #pragma unroll
    for (int nt = 0; nt < 4; ++nt){
      int n  = nt*16 + l15;
      int ch = i*4 + q4;
      v8s bf = *(const v8s*)&As[n*512 + ((ch ^ (n & 7))*8)];
      #pragma unroll
      for (int mt = 0; mt < 4; ++mt)
        acc[mt][nt] = __builtin_amdgcn_mfma_f32_16x16x32_bf16(aA[mt], bf, acc[mt][nt], 0,0,0);
    }
    #pragma unroll
    for (int mt = 0; mt < 4; ++mt) aA[mt] = aN[mt];
  }
}

// one-shot variant (tree levels)
__device__ __forceinline__ void step_mfma64_one(f32x4 acc[4][4],
    const ushort_t* __restrict__ As, const ushort_t* __restrict__ base,
    int wv, int l15, int q4){
  v8s aA[4], aN[4];
  #pragma unroll
  for (int mt = 0; mt < 4; ++mt) aA[mt] = *(const v8s*)&base[mt*512];
  #pragma unroll
  for (int i = 0; i < 16; ++i){
    if (i < 15){
      #pragma unroll
      for (int mt = 0; mt < 4; ++mt)
        aN[mt] = *(const v8s*)&base[(size_t)(i + 1)*16384 + mt*512];
    }
    #pragma unroll
    for (int nt = 0; nt < 4; ++nt){
      int n  = nt*16 + l15;
      int ch = i*4 + q4;
      v8s bf = *(const v8s*)&As[n*512 + ((ch ^ (n & 7))*8)];
      #pragma unroll
      for (int mt = 0; mt < 4; ++mt)
        acc[mt][nt] = __builtin_amdgcn_mfma_f32_16x16x32_bf16(aA[mt], bf, acc[mt][nt], 0,0,0);
    }
    #pragma unroll
    for (int mt = 0; mt < 4; ++mt) aA[mt] = aN[mt];
  }
}

__device__ __forceinline__ void load_strip64(ushort_t* As,
    const ushort_t* __restrict__ src, int rowbase, int tid){
  #pragma unroll
  for (int q = 0; q < 8; ++q){
    int F = tid + q*512;
    int m = F >> 6, p = F & 63;
    *(v8s*)&As[m*512 + p*8] =
      *(const v8s*)&src[(size_t)(rowbase + m)*NSTATE + ((p ^ (m & 7))*8)];
  }
}

__device__ __forceinline__ void writeback64(ushort_t* As, f32x4 acc[4][4],
    int wv, int l15, int q4){
  #pragma unroll
  for (int nt = 0; nt < 4; ++nt){
    int n = nt*16 + l15;
    #pragma unroll
    for (int mt = 0; mt < 4; ++mt){
      int col = wv*64 + mt*16 + q4*4;
      ushort4 h;
      h.x = f2bf(acc[mt][nt][0]); h.y = f2bf(acc[mt][nt][1]);
      h.z = f2bf(acc[mt][nt][2]); h.w = f2bf(acc[mt][nt][3]);
      int p = (col >> 3) ^ (n & 7);
      *(ushort4*)&As[n*512 + p*8 + (col & 7)] = h;
    }
  }
}

// final store: even -> row-major; odd -> fragment-major transposed
__device__ __forceinline__ void store_out64(ushort_t* slot, f32x4 acc[4][4],
    int rowbase, bool even, int lane, int wv, int l15, int q4){
  if (even){
    #pragma unroll
    for (int nt = 0; nt < 4; ++nt){
      int grow = rowbase + nt*16 + l15;
      #pragma unroll
      for (int mt = 0; mt < 4; ++mt){
        int gcol = wv*64 + mt*16 + q4*4;
        ushort4 h;
        h.x = f2bf(acc[mt][nt][0]); h.y = f2bf(acc[mt][nt][1]);
        h.z = f2bf(acc[mt][nt][2]); h.w = f2bf(acc[mt][nt][3]);
        *(ushort4*)&slot[(size_t)grow*NSTATE + gcol] = h;
      }
    }
  } else {
    // 4x4 quad butterfly (HW-proven rounds 5-8): lane ends with
    // d[i] = C[G0+i][mcol], contiguous in fragT (k = G0..G0+3)
    #pragma unroll
    for (int nt = 0; nt < 4; ++nt){
      int G0 = rowbase + nt*16 + (l15 & 12);
      #pragma unroll
      for (int mt = 0; mt < 4; ++mt){
        float v0 = acc[mt][nt][0], v1 = acc[mt][nt][1];
        float v2 = acc[mt][nt][2], v3 = acc[mt][nt][3];
        float s0 = __shfl_xor(v0, 2), s1 = __shfl_xor(v1, 2);
        float s2 = __shfl_xor(v2, 2), s3 = __shfl_xor(v3, 2);
        const bool h2 = lane & 2;
        float c0 = h2 ? s2 : v0, c1 = h2 ? s3 : v1;
        float c2 = h2 ? v2 : s0, c3 = h2 ? v3 : s1;
        float u0 = __shfl_xor(c0, 1), u1 = __shfl_xor(c1, 1);
        float u2 = __shfl_xor(c2, 1), u3 = __shfl_xor(c3, 1);
        const bool h1 = lane & 1;
        float d0 = h1 ? u1 : c0, d1 = h1 ? c1 : u0;
        float d2 = h1 ? u3 : c2, d3 = h1 ? c3 : u2;
        int mcol = wv*64 + mt*16 + q4*4 + (lane & 3);
        ushort4 h;
        h.x = f2bf(d0); h.y = f2bf(d1); h.z = f2bf(d2); h.w = f2bf(d3);
        *(ushort4*)&slot[fragT_idx(mcol, G0)] = h;
      }
    }
  }
}

// Chains. Hierarchical mapping (o = b>>3, xcd = b&7):
//   c     = (o>>6)*64 + ((o>>2)&7)*8 + xcd      (bijective for nchain>=64)
//   strip = (o&3)*2 + ((o>>5)&1)
// Guarantees: all 8 strips of a chain on one XCD (L2 reuse, 4 MiB set);
// strips (2t,2t+1) at blocks b,b+256 -> same CU slot -> shared L1 A-stream.
__global__ __launch_bounds__(512, 4) void k_chain3(
    const int* __restrict__ tokens, const ushort_t* __restrict__ Tb,
    const ushort_t* __restrict__ Tf, ushort_t* __restrict__ Lout, int W){
  extern __shared__ __align__(16) ushort_t As[];   // 64x512 bf16
  const int b   = blockIdx.x;
  const int o   = b >> 3;
  const int c   = (o >> 6)*64 + ((o >> 2) & 7)*8 + (b & 7);
  const int strip = (o & 3)*2 + ((o >> 5) & 1);
  const int rowbase = strip * 64;
  const int tid  = threadIdx.x;
  const int lane = tid & 63;
  const int wv   = tid >> 6;
  const int l15  = lane & 15;
  const int q4   = lane >> 4;
  const int t0   = c * W;
  const size_t laneoff = ((size_t)(wv*64 + l15)*4 + q4)*8;

  load_strip64(As, Tb + (size_t)tokens[t0] * MS, rowbase, tid);
  const ushort_t* basek = Tf + (size_t)tokens[t0 + 1] * MS + laneoff;
  v8s aA[4];
  #pragma unroll
  for (int mt = 0; mt < 4; ++mt) aA[mt] = *(const v8s*)&basek[mt*512];
  __syncthreads();

  for (int k = 1; k < W; ++k){
    const ushort_t* baseN = (k + 1 < W)
        ? (Tf + (size_t)tokens[t0 + k + 1] * MS + laneoff) : basek;
    f32x4 acc[4][4];
    #pragma unroll
    for (int mt = 0; mt < 4; ++mt)
      #pragma unroll
      for (int nt = 0; nt < 4; ++nt) acc[mt][nt] = (f32x4){0.f,0.f,0.f,0.f};
    step_mfma64_pf(acc, As, basek, baseN, aA, wv, l15, q4);
    __syncthreads();                   // strip reads done
    if (k < W - 1){
      writeback64(As, acc, wv, l15, q4);
      __syncthreads();                 // new strip visible
    } else {
      store_out64(Lout + (size_t)c * MS, acc, rowbase, !(c & 1), lane, wv, l15, q4);
    }
    basek = baseN;
  }
}

// One tree level: Ldst[j] = Lsrc[2j](RM) @ Lsrc[2j+1](fragT), 8 strips/node.
// j = b%nodes, strip = b/nodes: blocks b,b+256 share node (CU pairing) and
// node fixes XCD for nodes%8==0.
__global__ __launch_bounds__(512, 4) void k_tree3(
    const ushort_t* __restrict__ Lsrc, ushort_t* __restrict__ Ldst, int nodes){
  extern __shared__ __align__(16) ushort_t As[];
  const int b = blockIdx.x;
  const int j = b % nodes;
  const int strip = b / nodes;
  const int rowbase = strip * 64;
  const int tid  = threadIdx.x;
  const int lane = tid & 63;
  const int wv   = tid >> 6;
  const int l15  = lane & 15;
  const int q4   = lane >> 4;
  const size_t laneoff = ((size_t)(wv*64 + l15)*4 + q4)*8;
  load_strip64(As, Lsrc + (size_t)(2*j) * MS, rowbase, tid);
  __syncthreads();
  f32x4 acc[4][4];
  #pragma unroll
  for (int mt = 0; mt < 4; ++mt)
    #pragma unroll
    for (int nt = 0; nt < 4; ++nt) acc[mt][nt] = (f32x4){0.f,0.f,0.f,0.f};
  step_mfma64_one(acc, As, Lsrc + (size_t)(2*j + 1) * MS + laneoff, wv, l15, q4);
  store_out64(Ldst + (size_t)j * MS, acc, rowbase, !(j & 1), lane, wv, l15, q4);
}

// transfer f32 -> Tb (bf16 row-major) + Tf (bf16 fragment-major transposed)
__global__ __launch_bounds__(256) void k_prep(const float* __restrict__ transfer,
                                              ushort_t* __restrict__ Tb,
                                              ushort_t* __restrict__ Tf){
  __shared__ ushort_t t[32*512];
  const int s = blockIdx.x >> 4;
  const int kk = blockIdx.x & 15;                  // K-band [32kk,+32)
  const int krows = kk * 32;
  const int tid = threadIdx.x;
  for (int idx = tid; idx < 32*512; idx += 256){
    int r = idx >> 9, n = idx & 511;
    ushort_t h = f2bf(transfer[(size_t)s*MS + (size_t)(krows + r)*NSTATE + n]);
    Tb[(size_t)s*MS + (size_t)(krows + r)*NSTATE + n] = h;
    t[r*512 + n] = h;
  }
  __syncthreads();
  for (int idx = tid; idx < 512*4; idx += 256){
    int n = idx >> 2, cc = idx & 3;
    v8s vv;
    #pragma unroll
    for (int jj = 0; jj < 8; ++jj) vv[jj] = (short)t[(cc*8 + jj)*512 + n];
    *(v8s*)&Tf[(size_t)s*MS + ((size_t)(kk*512 + n)*4 + cc)*8] = vv;
  }
}

// ---------------------------------------------------------------------------
// Fallback path (no big-LDS): proven gemm_step with fragT B.
// ---------------------------------------------------------------------------
__device__ __forceinline__ void gl_lds16(const void* g, void* l){
  __builtin_amdgcn_global_load_lds(
      (const __attribute__((address_space(1))) unsigned int*)g,
      (__attribute__((address_space(3))) unsigned int*)l, 16, 0, 0);
}

__device__ void gemm_step(const ushort_t* __restrict__ A,
                          const ushort_t* __restrict__ Bf,
                          ushort_t* dRM, ushort_t* dT, int rowbase){
  __shared__ __align__(16) ushort_t ldsA[128*64];
  __shared__ __align__(16) ushort_t ldsB[128*64];
  const int tid  = threadIdx.x;
  const int lane = tid & 63;
  const int w    = tid >> 6;
  const int l15  = lane & 15;
  const int koff = (lane >> 4) * 8;

  __threadfence_block();

  for (int p = 0; p < 4; ++p){
    f32x4 acc[2][8];
    #pragma unroll
    for (int rt = 0; rt < 2; ++rt)
      #pragma unroll
      for (int ct = 0; ct < 8; ++ct) acc[rt][ct] = (f32x4){0.f,0.f,0.f,0.f};

    for (int kk = 0; kk < 8; ++kk){
      __syncthreads();
      #pragma unroll
      for (int q = 0; q < 4; ++q){
        int idx = tid + q*256;
        int rr = idx >> 3, cch = idx & 7;
        gl_lds16(&A [(size_t)(rowbase + rr)*NSTATE + kk*64 + cch*8], &ldsA[idx*8]);
        gl_lds16(&Bf[fragT_idx(p*128 + rr, kk*64 + cch*8)], &ldsB[idx*8]);
      }
      __syncthreads();
      #pragma unroll
      for (int kc = 0; kc < 2; ++kc){
        v8s a0 = *(const v8s*)&ldsA[(w*32 +      l15)*64 + kc*32 + koff];
        v8s a1 = *(const v8s*)&ldsA[(w*32 + 16 + l15)*64 + kc*32 + koff];
        #pragma unroll
        for (int ct = 0; ct < 8; ++ct){
          v8s bb = *(const v8s*)&ldsB[(ct*16 + l15)*64 + kc*32 + koff];
          acc[0][ct] = __builtin_amdgcn_mfma_f32_16x16x32_bf16(a0, bb, acc[0][ct], 0,0,0);
          acc[1][ct] = __builtin_amdgcn_mfma_f32_16x16x32_bf16(a1, bb, acc[1][ct], 0,0,0);
        }
      }
    }
    const int rb = rowbase + w*32 + (lane >> 4)*4;
    #pragma unroll
    for (int rt = 0; rt < 2; ++rt)
      #pragma unroll
      for (int ct = 0; ct < 8; ++ct)
        #pragma unroll
        for (int i = 0; i < 4; ++i){
          int grow = rb + rt*16 + i;
          int gcol = p*128 + ct*16 + l15;
          ushort_t h = f2bf(acc[rt][ct][i]);
          if (dRM) dRM[(size_t)grow*NSTATE + gcol] = h;
          if (dT)  dT [fragT_idx(gcol, grow)] = h;
        }
  }
  __syncthreads();
}

__global__ __launch_bounds__(256) void k_chain(const int* __restrict__ tokens,
    const ushort_t* __restrict__ Tb, const ushort_t* __restrict__ Tf,
    ushort_t* ping, ushort_t* pong, ushort_t* Lout, int W){
  const int c = blockIdx.x >> 2;
  const int r = blockIdx.x & 3;
  const int t0 = c * W;
  ushort_t* bufA = ping + (size_t)c * MS;
  ushort_t* bufB = pong + (size_t)c * MS;
  for (int k = 1; k < W; ++k){
    const ushort_t* Asrc = (k == 1) ? Tb + (size_t)tokens[t0] * MS
                                    : (((k - 1) & 1) ? bufA : bufB);
    ushort_t *dRM, *dT;
    if (k == W - 1){
      ushort_t* slot = Lout + (size_t)c * MS;
      dRM = (c & 1) ? nullptr : slot;
      dT  = (c & 1) ? slot    : nullptr;
    } else {
      dRM = (k & 1) ? bufA : bufB; dT = nullptr;
    }
    gemm_step(Asrc, Tf + (size_t)tokens[t0 + k] * MS, dRM, dT, r * 128);
  }
}

__global__ __launch_bounds__(256) void k_tree(const ushort_t* __restrict__ Lsrc,
                                              ushort_t* __restrict__ Ldst){
  const int j = blockIdx.x >> 2, r = blockIdx.x & 3;
  const ushort_t* A  = Lsrc + (size_t)(2*j)     * MS;
  const ushort_t* Bf = Lsrc + (size_t)(2*j + 1) * MS;
  ushort_t* slot = Ldst + (size_t)j * MS;
  gemm_step(A, Bf, (j & 1) ? nullptr : slot, (j & 1) ? slot : nullptr, r * 128);
}

// Boundary vectors u_g via binary decomposition over tree levels baseLvl..11.
// Node index (pos>>p) always even -> row-major form available.
__global__ __launch_bounds__(512) void k_descent(const float* __restrict__ start,
    const ushort_t* __restrict__ lvl4, const ushort_t* __restrict__ Upper,
    float* __restrict__ u, int baseLvl){
  __shared__ float v[NSTATE];
  const int upOff[7] = {0,128,192,224,240,248,252};
  const int g = blockIdx.x, tid = threadIdx.x;
  v[tid] = start[tid];
  __syncthreads();
  int pos = 0;
  for (int p = 11 - baseLvl; p >= 0; --p){
    if ((g >> p) & 1){
      const int L = baseLvl + p;
      const ushort_t* arr = (L == 4) ? lvl4 : (Upper + (size_t)upOff[L-5] * MS);
      const ushort_t* M = arr + (size_t)(pos >> p) * MS;
      float a0=0.f,a1=0.f,a2=0.f,a3=0.f;
      #pragma unroll 4
      for (int i = 0; i < NSTATE; i += 4){
        a0 += v[i  ] * bf2f(M[(size_t)(i  )*NSTATE + tid]);
        a1 += v[i+1] * bf2f(M[(size_t)(i+1)*NSTATE + tid]);
        a2 += v[i+2] * bf2f(M[(size_t)(i+2)*NSTATE + tid]);
        a3 += v[i+3] * bf2f(M[(size_t)(i+3)*NSTATE + tid]);
      }
      __syncthreads();
      v[tid] = (a0+a1)+(a2+a3);
      __syncthreads();
      pos += 1 << p;
    }
  }
  u[(size_t)g*NSTATE + tid] = v[tid];
}

// Per-segment replay with fragT vector loads: thread tid = output column m;
// M[k][m] for 32 consecutive k is 64 contiguous bytes in Tf.
__global__ __launch_bounds__(512) void k_phase2(const int* __restrict__ tokens,
    const float* __restrict__ u, const ushort_t* __restrict__ Tf,
    const float* __restrict__ probs, float* __restrict__ partials,
    float* __restrict__ out, int SEG){
  __shared__ float v[NSTATE];
  __shared__ float redc[8], redm[8];
  __shared__ float fac, minv;
  const int g = blockIdx.x, tid = threadIdx.x;
  v[tid] = u[(size_t)g*NSTATE + tid];
  float pp = 1.f;
  __syncthreads();
  for (int k = 0; k < SEG; ++k){
    const int tok = tokens[g*SEG + k];
    float a = v[tid];
    float bb = a * probs[(size_t)tok*NSTATE + tid];
    #pragma unroll
    for (int o = 32; o > 0; o >>= 1){
      a  += __shfl_down(a, o);
      bb += __shfl_down(bb, o);
    }
    if ((tid & 63) == 0){ redm[tid >> 6] = a; redc[tid >> 6] = bb; }
    __syncthreads();
    if (tid == 0){
      float m = 0.f, cc = 0.f;
      #pragma unroll
      for (int q = 0; q < 8; ++q){ m += redm[q]; cc += redc[q]; }
      fac = cc / m;
    }
    __syncthreads();
    pp *= fac;
    const ushort_t* Mf = Tf + (size_t)tok * MS + (size_t)tid * 32;
    float a0=0.f,a1=0.f,a2=0.f,a3=0.f;
    for (int bnd = 0; bnd < 16; ++bnd){
      const v8s* pv = (const v8s*)&Mf[(size_t)bnd*16384];
      v8s h0 = pv[0], h1 = pv[1], h2 = pv[2], h3 = pv[3];
      const float* vb = &v[bnd*32];
      #pragma unroll
      for (int j = 0; j < 8; ++j){
        a0 += vb[j     ] * bf2f((ushort_t)h0[j]);
        a1 += vb[j +  8] * bf2f((ushort_t)h1[j]);
        a2 += vb[j + 16] * bf2f((ushort_t)h2[j]);
        a3 += vb[j + 24] * bf2f((ushort_t)h3[j]);
      }
    }
    __syncthreads();
    v[tid] = (a0+a1)+(a2+a3);
    __syncthreads();
  }
  if (tid == 0) partials[g] = pp;
  if (g == gridDim.x - 1){
    float a = v[tid];
    #pragma unroll
    for (int o = 32; o > 0; o >>= 1) a += __shfl_down(a, o);
    if ((tid & 63) == 0) redm[tid >> 6] = a;
    __syncthreads();
    if (tid == 0){
      float m = 0.f;
      #pragma unroll
      for (int q = 0; q < 8; ++q) m += redm[q];
      minv = 1.f / m;
    }
    __syncthreads();
    out[tid] = v[tid] * minv;
  }
}

__global__ __launch_bounds__(512) void k_finish(const float* __restrict__ partials,
    const float* __restrict__ finals, float* out, int G){
  __shared__ float red[8];
  const int tid = threadIdx.x;
  float x = out[tid] * finals[tid];
  #pragma unroll
  for (int o = 32; o > 0; o >>= 1) x += __shfl_down(x, o);
  if ((tid & 63) == 0) red[tid >> 6] = x;
  __syncthreads();
  if (tid == 0){
    float s = 0.f;
    for (int q = 0; q < 8; ++q) s += red[q];
    float pp = 1.f;
    for (int q = 0; q < G; ++q) pp *= partials[q];
    out[NSTATE] = pp * s;
  }
}

__global__ __launch_bounds__(512) void k_fallback(const int* __restrict__ tokens,
    const float* __restrict__ start, const float* __restrict__ transfer,
    const float* __restrict__ probs, const float* __restrict__ finals,
    float* out){
  __shared__ float v[NSTATE];
  __shared__ float red[9];
  const int tid = threadIdx.x;
  v[tid] = start[tid];
  float pp = 1.f;
  __syncthreads();
  for (int t = 0; t < LTOK; ++t){
    const int tok = tokens[t];
    float x = v[tid] * probs[(size_t)tok*NSTATE + tid];
    #pragma unroll
    for (int o = 32; o > 0; o >>= 1) x += __shfl_down(x, o);
    if ((tid & 63) == 0) red[tid >> 6] = x;
    __syncthreads();
    if (tid == 0){
      float cc = 0.f;
      for (int q = 0; q < 8; ++q) cc += red[q];
      red[8] = cc;
    }
    __syncthreads();
    pp *= red[8];
    const float* M = transfer + (size_t)tok * MS;
    float acc = 0.f;
    #pragma unroll 8
    for (int i = 0; i < NSTATE; ++i) acc += v[i] * M[(size_t)i*NSTATE + tid];
    __syncthreads();
    v[tid] = acc;
    __syncthreads();
  }
  out[tid] = v[tid];
  float x = v[tid] * finals[tid];
  #pragma unroll
  for (int o = 32; o > 0; o >>= 1) x += __shfl_down(x, o);
  if ((tid & 63) == 0) red[tid >> 6] = x;
  __syncthreads();
  if (tid == 0){
    float s = 0.f;
    for (int q = 0; q < 8; ++q) s += red[q];
    out[NSTATE] = pp * s;
  }
}

extern "C" void kernel_launch(void* const* d_in, const int* in_sizes, int n_in,
                              void* d_out, int out_size, void* d_ws, size_t ws_size,
                              hipStream_t stream) {
  const int*   tokens   = (const int*)  d_in[0];
  const float* start    = (const float*)d_in[1];
  const float* transfer = (const float*)d_in[2];
  const float* probs    = (const float*)d_in[3];
  const float* finals   = (const float*)d_in[4];
  float* out = (float*)d_out;
  (void)in_sizes; (void)n_in; (void)out_size;

  const size_t C2 = MS * 2;
  size_t off = 0;
  const size_t o_Tb    = off; off += C2 * NSYM;    // 64 MiB
  const size_t o_Tf    = off; off += C2 * NSYM;    // 64 MiB
  const size_t o_Upper = off; off += C2 * 254;     // 127 MiB (tree levels 5..11)
  const size_t o_u     = off; off += (size_t)256 * NSTATE * 4;
  const size_t o_part  = off; off += 256 * 4 + 256;
  const size_t common  = off;                      // ~255.4 MiB

  const int LDSBYTES = 64*512*2;                   // 65536
  bool bigLds =
    hipFuncSetAttribute(reinterpret_cast<const void*>(k_chain3),
        hipFuncAttributeMaxDynamicSharedMemorySize, LDSBYTES) == hipSuccess &&
    hipFuncSetAttribute(reinterpret_cast<const void*>(k_tree3),
        hipFuncAttributeMaxDynamicSharedMemorySize, LDSBYTES) == hipSuccess;

  char* ws = (char*)d_ws;
  ushort_t* Tb    = (ushort_t*)(ws + o_Tb);
  ushort_t* Tf    = (ushort_t*)(ws + o_Tf);
  ushort_t* Upper = (ushort_t*)(ws + o_Upper);
  float*    u     = (float*)   (ws + o_u);
  float*    parts = (float*)   (ws + o_part);

  const int upOff[7] = {0,128,192,224,240,248,252};
  ushort_t* lvl[12] = {nullptr};
  for (int l = 5; l <= 11; ++l) lvl[l] = Upper + (size_t)upOff[l-5] * MS;

  int W = 0, sLvl = 0;
  size_t oo = common;
  if (bigLds){
    if      (ws_size >= common + C2 * (512 + 256)) { W = 8;  sLvl = 3; }
    else if (ws_size >= common + C2 * 256)         { W = 16; sLvl = 4; }
    else if (ws_size >= common)                    { W = 32; sLvl = 5; }
    if (W){
      if (W == 8) { lvl[3] = (ushort_t*)(ws + oo); oo += C2 * 512; }
      if (W <= 16){ lvl[4] = (ushort_t*)(ws + oo); oo += C2 * 256; }
    }
  } else {
    if (ws_size >= common + C2 * 256) { W = 32; sLvl = 5; }
  }
  if (!W){
    k_fallback<<<1, 512, 0, stream>>>(tokens, start, transfer, probs, finals, out);
    return;
  }
  const int nchain = LTOK / W;
  const int G    = lvl[4] ? 256 : 128;
  const int SEGc = LTOK / G;
  const int baseLvl = lvl[4] ? 4 : 5;

  k_prep<<<NSYM * 16, 256, 0, stream>>>(transfer, Tb, Tf);
  if (bigLds){
    k_chain3<<<nchain * 8, 512, LDSBYTES, stream>>>(tokens, Tb, Tf, lvl[sLvl], W);
    for (int l = sLvl; l < 11; ++l){
      const int cntNext = LTOK >> (l + 1);
      k_tree3<<<cntNext * 8, 512, LDSBYTES, stream>>>(lvl[l], lvl[l + 1], cntNext);
    }
  } else {
    ushort_t* ping = (ushort_t*)(ws + oo); oo += C2 * nchain;
    ushort_t* pong = (ushort_t*)(ws + oo); oo += C2 * nchain;
    k_chain<<<nchain * 4, 256, 0, stream>>>(tokens, Tb, Tf, ping, pong, lvl[sLvl], W);
    for (int l = sLvl; l < 11; ++l){
      const int cntNext = LTOK >> (l + 1);
      k_tree<<<cntNext * 4, 256, 0, stream>>>(lvl[l], lvl[l + 1]);
    }
  }
  k_descent<<<G, 512, 0, stream>>>(start, lvl[4], Upper, u, baseLvl);
  k_phase2 <<<G, 512, 0, stream>>>(tokens, u, Tf, probs, parts, out, SEGc);
  k_finish <<<1, 512, 0, stream>>>(parts, finals, out, G);
}